// Round 7
// baseline (534.779 us; speedup 1.0000x reference)
//
#include <hip/hip_runtime.h>
#include <hip/hip_bf16.h>
#include <stdint.h>

#define B_ 4
#define S_ 1024
#define D_ 1024
#define H_ 4096
#define E_ 8
#define T_ (B_*S_)   // 4096 tokens

#define BM 256
#define BN 256
#define BK 64        // 128 bytes of bf16 per row per K-tile
#define MAXMB 48

typedef __bf16 bf16x8 __attribute__((ext_vector_type(8)));
typedef float f32x4 __attribute__((ext_vector_type(4)));
typedef unsigned short ushort8 __attribute__((ext_vector_type(8)));

__device__ __forceinline__ unsigned short f2bf(float f) {
  union { float f; uint32_t u; } v; v.f = f;
  uint32_t u = v.u;
  u += 0x7fff + ((u >> 16) & 1);   // round-to-nearest-even
  return (unsigned short)(u >> 16);
}

// async global->LDS, 16B per lane; LDS dest is WAVE-UNIFORM base, HW scatters lane*16
__device__ __forceinline__ void gl16(const void* g, void* l) {
  __builtin_amdgcn_global_load_lds(
      (const __attribute__((address_space(1))) void*)g,
      (__attribute__((address_space(3))) void*)l,
      16, 0, 0);
}
#define MEMFENCE asm volatile("" ::: "memory")

// ---------------- x fp32 -> bf16 ----------------
__global__ __launch_bounds__(256) void conv_x_kernel(
    const float* __restrict__ x, unsigned short* __restrict__ xb) {
  size_t i = ((size_t)blockIdx.x * 256 + threadIdx.x) * 8;
  const float4* s = (const float4*)(x + i);
  float4 v0 = s[0], v1 = s[1];
  ushort8 w;
  w[0]=f2bf(v0.x); w[1]=f2bf(v0.y); w[2]=f2bf(v0.z); w[3]=f2bf(v0.w);
  w[4]=f2bf(v1.x); w[5]=f2bf(v1.y); w[6]=f2bf(v1.z); w[7]=f2bf(v1.w);
  *(ushort8*)(xb + i) = w;
}

// ---------------- W fp32 [E][R][C] -> bf16 [E][C][R] ----------------
__global__ __launch_bounds__(256) void transpose_conv(
    const float* __restrict__ in, unsigned short* __restrict__ outp,
    int R, int C) {
  __shared__ float tile[64][68];
  const int e = blockIdx.z;
  const size_t eoff = (size_t)e * R * C;
  const int r0 = blockIdx.y * 64, c0 = blockIdx.x * 64;
  const int t = threadIdx.x;
  {
    const int r = t >> 2, cq = (t & 3) * 16;
    const float4* s4 = (const float4*)(in + eoff + (size_t)(r0 + r) * C + (c0 + cq));
#pragma unroll
    for (int i = 0; i < 4; ++i)
      *(float4*)&tile[r][cq + i * 4] = s4[i];
  }
  __syncthreads();
  {
    const int c = t >> 2, r8 = (t & 3) * 16;
    unsigned short* dst = outp + eoff + (size_t)(c0 + c) * R + (r0 + r8);
    ushort8 w0, w1;
#pragma unroll
    for (int j = 0; j < 8; ++j) {
      w0[j] = f2bf(tile[r8 + j][c]);
      w1[j] = f2bf(tile[r8 + 8 + j][c]);
    }
    *(ushort8*)dst = w0;
    *(ushort8*)(dst + 8) = w1;
  }
}

// ---------------- gating: scores + top-2 routing ----------------
__global__ __launch_bounds__(256) void gating_kernel(
    const float* __restrict__ x, const float* __restrict__ Wg,
    const float* __restrict__ bg, float* __restrict__ scores,
    int* __restrict__ cnt, int* __restrict__ lists) {
  int t = blockIdx.x * 4 + (threadIdx.x >> 6);
  int l = threadIdx.x & 63;
  float acc[E_];
#pragma unroll
  for (int e = 0; e < E_; ++e) acc[e] = 0.f;
  const float* xr = x + (size_t)t * D_;
  for (int k = l; k < D_; k += 64) {
    float xv = xr[k];
    const float4* w = (const float4*)(Wg + (size_t)k * E_);
    float4 w0 = w[0], w1 = w[1];
    acc[0] += xv * w0.x; acc[1] += xv * w0.y; acc[2] += xv * w0.z; acc[3] += xv * w0.w;
    acc[4] += xv * w1.x; acc[5] += xv * w1.y; acc[6] += xv * w1.z; acc[7] += xv * w1.w;
  }
#pragma unroll
  for (int off = 32; off > 0; off >>= 1)
#pragma unroll
    for (int e = 0; e < E_; ++e) acc[e] += __shfl_xor(acc[e], off, 64);
  if (l == 0) {
    float s[E_];
#pragma unroll
    for (int e = 0; e < E_; ++e) {
      s[e] = acc[e] + bg[e];
      scores[(size_t)t * E_ + e] = s[e];
    }
    int i1 = 0; float m1 = -1e30f;
#pragma unroll
    for (int e = 0; e < E_; ++e) if (s[e] > m1) { m1 = s[e]; i1 = e; }
    int i2 = -1; float m2 = -1e30f;
#pragma unroll
    for (int e = 0; e < E_; ++e) if (e != i1 && s[e] > m2) { m2 = s[e]; i2 = e; }
    int p1 = atomicAdd(&cnt[i1], 1); lists[i1 * T_ + p1] = t;
    int p2 = atomicAdd(&cnt[i2], 1); lists[i2 * T_ + p2] = t;
  }
}

// scan + dense M-tile table: mbtab[i] = (e<<16)|local_tile, -1 past end.
__global__ void scan_kernel(const int* __restrict__ cnt, int* __restrict__ off,
                            int* __restrict__ mbtab) {
  if (threadIdx.x == 0) {
    int o = 0, nb = 0;
    for (int e = 0; e < E_; ++e) {
      off[e] = o; o += cnt[e];
      int ntl = (cnt[e] + BM - 1) / BM;
      for (int i = 0; i < ntl; ++i) mbtab[nb++] = (e << 16) | i;
    }
    for (; nb < MAXMB; ++nb) mbtab[nb] = -1;
  }
}

// ---------------- grouped per-expert GEMM: 256^2, m201-style 8-phase ----------
// 512 thr = 8 waves (2M x 4N), per-wave 128x64 output (8x4 frags of 16x16).
// LDS: 2 dbuf x (A 32KB + B 32KB) = 128 KB. Rows 128B; swizzle ((row&7)<<4)
// baked into per-lane GLOBAL src (gload_lds writes linearly); same XOR on reads.
// Per iteration (2 K-tiles v0=2p buf0, v1=2p+1 buf1), 8 phases; each phase:
// {<=12 ds_read | 1 half-tile stage (2 gl16) | bar | lgkm0 | 16 MFMA | [bar]}.
// Staging: ph0,1 -> B of 2p+1 (buf1); ph2,3 -> A of 2p+2 (buf0);
//          ph4,5 -> B of 2p+2 (buf0); ph6,7 -> A of 2p+3 (buf1).
// Counted vmcnt(4) at ph3/ph7 only (4 newest loads stay in flight); the
// vmcnt+barrier certifies all older stages landed chip-wide before reads.
template <int LAYER, int SPLITK>
__global__ __launch_bounds__(512, 2) void ffn_gemm(
    const unsigned short* __restrict__ xb,
    const unsigned short* __restrict__ hbuf,
    const unsigned short* __restrict__ WT,
    const float* __restrict__ bias,
    const int* __restrict__ cnt, const int* __restrict__ off,
    const int* __restrict__ lists, const int* __restrict__ mbtab,
    unsigned short* __restrict__ hout,
    float* __restrict__ out)
{
  constexpr int K = (LAYER == 1) ? D_ : H_;
  constexpr int N = (LAYER == 1) ? H_ : D_;
  constexpr int KS = K / SPLITK;
  constexpr int NT = KS / BK;      // 16 for both GEMMs
  constexpr int P  = NT / 2;
  constexpr int NX = N / BN;

  const int ent = mbtab[blockIdx.y];
  if (ent < 0) return;
  const int e  = ent >> 16;
  const int m0 = (ent & 0xffff) * BM;
  const int nt_ = blockIdx.x % NX;
  const int sp  = blockIdx.x / NX;
  const int n0  = nt_ * BN;
  const int k0  = sp * KS;
  const int count = cnt[e];
  const int oe = off[e];
  const int* lst = lists + e * T_;

  __shared__ unsigned short sA[2][BM * BK];   // 2 x 32 KB
  __shared__ unsigned short sB[2][BN * BK];   // 2 x 32 KB

  const int tid  = threadIdx.x;
  const int lane = tid & 63;
  const int wv   = tid >> 6;
  const int wm   = (wv >> 2) * 128;
  const int wn   = (wv & 3) * 64;

  // staging: issue i covers rows i*64 + wv*8 + srow
  const int srow   = lane >> 3;
  const int schunk = (lane & 7) * 16;
  const int sgoff  = schunk ^ (srow << 4);

  const char* arow[4];
  const char* brow[4];
#pragma unroll
  for (int i = 0; i < 4; ++i) {
    int r  = i * 64 + wv * 8 + srow;
    int gr = m0 + r;
    if (LAYER == 1) {
      int tok = (gr < count) ? lst[gr] : lst[m0];
      arow[i] = (const char*)(xb + (size_t)tok * K + k0);
    } else {
      int rr = (gr < count) ? gr : m0;
      arow[i] = (const char*)(hbuf + (size_t)(oe + rr) * K + k0);
    }
    brow[i] = (const char*)(WT + (size_t)e * N * K + (size_t)(n0 + r) * K + k0);
  }

  // stage one A-half (h=0,1) of K-tile t into buffer bb
  auto stA = [&](int bb, int t, int h) {
    gl16(arow[2*h]   + t * 128 + sgoff, (char*)&sA[bb][0] + ((2*h)   * 64 + wv * 8) * 128);
    gl16(arow[2*h+1] + t * 128 + sgoff, (char*)&sA[bb][0] + ((2*h+1) * 64 + wv * 8) * 128);
  };
  auto stB = [&](int bb, int t, int h) {
    gl16(brow[2*h]   + t * 128 + sgoff, (char*)&sB[bb][0] + ((2*h)   * 64 + wv * 8) * 128);
    gl16(brow[2*h+1] + t * 128 + sgoff, (char*)&sB[bb][0] + ((2*h+1) * 64 + wv * 8) * 128);
  };

  // fragment addressing
  const int lrow = lane & 15;
  const int kg   = lane >> 4;
  const int fswz = (lrow & 7) << 4;
  auto frag = [&](const char* base, int row, int ks) {
    return *(const bf16x8*)(base + row * 128 + ((ks * 64 + kg * 16) ^ fswz));
  };

  f32x4 acc[8][4];
#pragma unroll
  for (int i = 0; i < 8; ++i)
#pragma unroll
    for (int j = 0; j < 4; ++j) acc[i][j] = (f32x4){0.f, 0.f, 0.f, 0.f};

  auto mm = [&](bf16x8 (&a)[4], bf16x8 (&b)[4], int mbase) {
    __builtin_amdgcn_s_setprio(1);
#pragma unroll
    for (int i = 0; i < 4; ++i)
#pragma unroll
      for (int j = 0; j < 4; ++j)
        acc[mbase + i][j] = __builtin_amdgcn_mfma_f32_16x16x32_bf16(a[i], b[j], acc[mbase + i][j], 0, 0, 0);
    __builtin_amdgcn_s_setprio(0);
  };

  // one half-iteration = 4 phases consuming buffer bb (one K-tile).
  // tB: K-tile whose B-halves are staged (into bb^1) at ph_a/ph_b
  // tA: K-tile whose A-halves are staged (into bb)   at ph_c/ph_d
  // vmN: -1 = no wait; else s_waitcnt vmcnt(vmN) before final barrier
  auto halfiter = [&](int bb, int tB, int tA, bool doB, bool doA, int vmN) {
    const char* SA = (const char*)&sA[bb][0];
    const char* SB = (const char*)&sB[bb][0];
    bf16x8 aL0[4], aH0[4], aL1[4], aH1[4], b0[4], b1[4];
    // ---- ph_a: read ks0 frags (12), stage B-half0, MFMA M0-3 ks0 ----
#pragma unroll
    for (int i = 0; i < 4; ++i) {
      aL0[i] = frag(SA, wm + i * 16 + lrow, 0);
      aH0[i] = frag(SA, wm + 64 + i * 16 + lrow, 0);
    }
#pragma unroll
    for (int j = 0; j < 4; ++j) b0[j] = frag(SB, wn + j * 16 + lrow, 0);
    if (doB) stB(bb ^ 1, tB, 0);
    MEMFENCE; __builtin_amdgcn_s_barrier(); MEMFENCE;
    asm volatile("s_waitcnt lgkmcnt(0)" ::: "memory");
    mm(aL0, b0, 0);
    // ---- ph_b: read ks1 frags (12), stage B-half1, MFMA M4-7 ks0 ----
#pragma unroll
    for (int i = 0; i < 4; ++i) {
      aL1[i] = frag(SA, wm + i * 16 + lrow, 1);
      aH1[i] = frag(SA, wm + 64 + i * 16 + lrow, 1);
    }
#pragma unroll
    for (int j = 0; j < 4; ++j) b1[j] = frag(SB, wn + j * 16 + lrow, 1);
    if (doB) stB(bb ^ 1, tB, 1);
    MEMFENCE; __builtin_amdgcn_s_barrier(); MEMFENCE;
    asm volatile("s_waitcnt lgkmcnt(0)" ::: "memory");
    mm(aH0, b0, 4);
    MEMFENCE; __builtin_amdgcn_s_barrier(); MEMFENCE;   // all reads of bb done
    // ---- ph_c: stage A-half0 (into bb, just freed), MFMA M0-3 ks1 ----
    if (doA) stA(bb, tA, 0);
    mm(aL1, b1, 0);
    // ---- ph_d: stage A-half1, MFMA M4-7 ks1, counted vmcnt, barrier ----
    if (doA) stA(bb, tA, 1);
    mm(aH1, b1, 4);
    if (vmN == 4)      { asm volatile("s_waitcnt vmcnt(4)" ::: "memory"); }
    else if (vmN == 0) { asm volatile("s_waitcnt vmcnt(0)" ::: "memory"); }
    MEMFENCE; __builtin_amdgcn_s_barrier(); MEMFENCE;
  };

  // ---- prologue: tile0 full -> buf0, tile1 A-halves -> buf1 (B comes ph0,1) ----
  stA(0, 0, 0); stA(0, 0, 1);
  stB(0, 0, 0); stB(0, 0, 1);
  stA(1, 1, 0); stA(1, 1, 1);
  asm volatile("s_waitcnt vmcnt(4)" ::: "memory");   // tile0 landed; tile1 A in flight
  MEMFENCE; __builtin_amdgcn_s_barrier(); MEMFENCE;

  for (int p = 0; p < P - 1; ++p) {
    halfiter(0, 2 * p + 1, 2 * p + 2, true, true, 4);
    halfiter(1, 2 * p + 2, 2 * p + 3, true, true, 4);
  }
  // tail iteration p = P-1: no tiles beyond NT-1 exist
  halfiter(0, NT - 1, 0, true, false, 0);
  halfiter(1, 0, 0, false, false, -1);

  // ---- epilogue ----
  const int rbase = 4 * kg;
#pragma unroll
  for (int i = 0; i < 8; ++i) {
#pragma unroll
    for (int r = 0; r < 4; ++r) {
      int row  = wm + i * 16 + rbase + r;
      int grow = m0 + row;
      if (grow < count) {
#pragma unroll
        for (int j = 0; j < 4; ++j) {
          int col  = wn + j * 16 + lrow;
          int gcol = n0 + col;
          float bv = (SPLITK == 1 || sp == 0) ? bias[(size_t)e * N + gcol] : 0.f;
          float v = acc[i][j][r] + bv;
          if (LAYER == 1) {
            v = v > 0.f ? v : 0.f;
            hout[(size_t)(oe + grow) * H_ + gcol] = f2bf(v);
          } else {
            int tok = lst[grow];
            atomicAdd(&out[(size_t)tok * D_ + gcol], v);
          }
        }
      }
    }
  }
}

extern "C" void kernel_launch(void* const* d_in, const int* in_sizes, int n_in,
                              void* d_out, int out_size, void* d_ws, size_t ws_size,
                              hipStream_t stream) {
  (void)in_sizes; (void)n_in; (void)out_size; (void)ws_size;
  const float* x  = (const float*)d_in[0];
  const float* W1 = (const float*)d_in[1];
  const float* b1 = (const float*)d_in[2];
  const float* W2 = (const float*)d_in[3];
  const float* b2 = (const float*)d_in[4];
  const float* Wg = (const float*)d_in[5];
  const float* bg = (const float*)d_in[6];

  float* out    = (float*)d_out;               // [T,D]
  float* scores = out + (size_t)T_ * D_;       // [T,E]

  char* ws = (char*)d_ws;
  int* cnt   = (int*)ws;                                   // 32 B
  int* off   = (int*)(ws + 32);                            // 32 B
  int* mbtab = (int*)(ws + 64);                            // 192 B (48 ints)
  int* lists = (int*)(ws + 256);                           // 128 KB
  unsigned short* xb   = (unsigned short*)(ws + 256 + 131072);             // 8 MB
  unsigned short* hbuf = (unsigned short*)(ws + 256 + 131072 + 8388608);   // 64 MB
  unsigned short* WT   = (unsigned short*)(ws + 256 + 131072 + 8388608 + 67108864); // 64 MB

  hipMemsetAsync(out, 0, (size_t)T_ * D_ * sizeof(float), stream);
  hipMemsetAsync(cnt, 0, 64, stream);

  conv_x_kernel<<<(T_ * D_) / (256 * 8), 256, 0, stream>>>(x, xb);
  gating_kernel<<<T_ / 4, 256, 0, stream>>>(x, Wg, bg, scores, cnt, lists);
  scan_kernel<<<1, 64, 0, stream>>>(cnt, off, mbtab);

  // W1 [E,1024,4096] -> W1T [E,4096,1024]
  transpose_conv<<<dim3(H_ / 64, D_ / 64, E_), 256, 0, stream>>>(W1, WT, D_, H_);
  ffn_gemm<1, 1><<<dim3(H_ / BN, MAXMB - 8), 512, 0, stream>>>(
      xb, hbuf, WT, b1, cnt, off, lists, mbtab, hbuf, nullptr);

  // W2 [E,4096,1024] -> W2T [E,1024,4096]  (reuses WT after gemm1)
  transpose_conv<<<dim3(D_ / 64, H_ / 64, E_), 256, 0, stream>>>(W2, WT, H_, D_);
  ffn_gemm<2, 4><<<dim3((D_ / BN) * 4, MAXMB - 8), 512, 0, stream>>>(
      xb, hbuf, WT, b2, cnt, off, lists, mbtab, nullptr, out);
}

// Round 8
// 512.705 us; speedup vs baseline: 1.0431x; 1.0431x over previous
//
#include <hip/hip_runtime.h>
#include <hip/hip_bf16.h>
#include <stdint.h>

#define B_ 4
#define S_ 1024
#define D_ 1024
#define H_ 4096
#define E_ 8
#define T_ (B_*S_)   // 4096 tokens

#define BM 256
#define BN 256
#define BK 64        // 128 bytes of bf16 per row per K-tile
#define MAXT1 640    // 40 mtiles x 16 nt
#define MAXT2 320    // 40 mtiles x 4 nt x 2 splits

typedef __bf16 bf16x8 __attribute__((ext_vector_type(8)));
typedef float f32x4 __attribute__((ext_vector_type(4)));
typedef unsigned short ushort8 __attribute__((ext_vector_type(8)));

__device__ __forceinline__ unsigned short f2bf(float f) {
  union { float f; uint32_t u; } v; v.f = f;
  uint32_t u = v.u;
  u += 0x7fff + ((u >> 16) & 1);   // round-to-nearest-even
  return (unsigned short)(u >> 16);
}

// async global->LDS, 16B per lane; LDS dest is WAVE-UNIFORM base, HW scatters lane*16
__device__ __forceinline__ void gl16(const void* g, void* l) {
  __builtin_amdgcn_global_load_lds(
      (const __attribute__((address_space(1))) void*)g,
      (__attribute__((address_space(3))) void*)l,
      16, 0, 0);
}
#define MEMFENCE asm volatile("" ::: "memory")

// ---------------- x fp32 -> bf16 ----------------
__global__ __launch_bounds__(256) void conv_x_kernel(
    const float* __restrict__ x, unsigned short* __restrict__ xb) {
  size_t i = ((size_t)blockIdx.x * 256 + threadIdx.x) * 8;
  const float4* s = (const float4*)(x + i);
  float4 v0 = s[0], v1 = s[1];
  ushort8 w;
  w[0]=f2bf(v0.x); w[1]=f2bf(v0.y); w[2]=f2bf(v0.z); w[3]=f2bf(v0.w);
  w[4]=f2bf(v1.x); w[5]=f2bf(v1.y); w[6]=f2bf(v1.z); w[7]=f2bf(v1.w);
  *(ushort8*)(xb + i) = w;
}

// ---------------- W fp32 [E][R][C] -> bf16 [E][C][R] ----------------
__global__ __launch_bounds__(256) void transpose_conv(
    const float* __restrict__ in, unsigned short* __restrict__ outp,
    int R, int C) {
  __shared__ float tile[64][68];
  const int e = blockIdx.z;
  const size_t eoff = (size_t)e * R * C;
  const int r0 = blockIdx.y * 64, c0 = blockIdx.x * 64;
  const int t = threadIdx.x;
  {
    const int r = t >> 2, cq = (t & 3) * 16;
    const float4* s4 = (const float4*)(in + eoff + (size_t)(r0 + r) * C + (c0 + cq));
#pragma unroll
    for (int i = 0; i < 4; ++i)
      *(float4*)&tile[r][cq + i * 4] = s4[i];
  }
  __syncthreads();
  {
    const int c = t >> 2, r8 = (t & 3) * 16;
    unsigned short* dst = outp + eoff + (size_t)(c0 + c) * R + (r0 + r8);
    ushort8 w0, w1;
#pragma unroll
    for (int j = 0; j < 8; ++j) {
      w0[j] = f2bf(tile[r8 + j][c]);
      w1[j] = f2bf(tile[r8 + 8 + j][c]);
    }
    *(ushort8*)dst = w0;
    *(ushort8*)(dst + 8) = w1;
  }
}

// ---------------- gating: scores + top-2 routing ----------------
__global__ __launch_bounds__(256) void gating_kernel(
    const float* __restrict__ x, const float* __restrict__ Wg,
    const float* __restrict__ bg, float* __restrict__ scores,
    int* __restrict__ cnt, int* __restrict__ lists) {
  int t = blockIdx.x * 4 + (threadIdx.x >> 6);
  int l = threadIdx.x & 63;
  float acc[E_];
#pragma unroll
  for (int e = 0; e < E_; ++e) acc[e] = 0.f;
  const float* xr = x + (size_t)t * D_;
  for (int k = l; k < D_; k += 64) {
    float xv = xr[k];
    const float4* w = (const float4*)(Wg + (size_t)k * E_);
    float4 w0 = w[0], w1 = w[1];
    acc[0] += xv * w0.x; acc[1] += xv * w0.y; acc[2] += xv * w0.z; acc[3] += xv * w0.w;
    acc[4] += xv * w1.x; acc[5] += xv * w1.y; acc[6] += xv * w1.z; acc[7] += xv * w1.w;
  }
#pragma unroll
  for (int off = 32; off > 0; off >>= 1)
#pragma unroll
    for (int e = 0; e < E_; ++e) acc[e] += __shfl_xor(acc[e], off, 64);
  if (l == 0) {
    float s[E_];
#pragma unroll
    for (int e = 0; e < E_; ++e) {
      s[e] = acc[e] + bg[e];
      scores[(size_t)t * E_ + e] = s[e];
    }
    int i1 = 0; float m1 = -1e30f;
#pragma unroll
    for (int e = 0; e < E_; ++e) if (s[e] > m1) { m1 = s[e]; i1 = e; }
    int i2 = -1; float m2 = -1e30f;
#pragma unroll
    for (int e = 0; e < E_; ++e) if (e != i1 && s[e] > m2) { m2 = s[e]; i2 = e; }
    int p1 = atomicAdd(&cnt[i1], 1); lists[i1 * T_ + p1] = t;
    int p2 = atomicAdd(&cnt[i2], 1); lists[i2 * T_ + p2] = t;
  }
}

// scan + locality-ordered task tables.
// task word: e<<20 | mt<<8 | sp<<4 | nt
// GEMM1 order: (e, ntgroup, mt, nt%4)  -> B-panel reuse across mt, A across nt, in L2
// GEMM2 order: (e, sp, mt, nt)         -> A-half reuse across nt, B-quarter across mt
__global__ void scan_kernel(const int* __restrict__ cnt, int* __restrict__ off,
                            int* __restrict__ hdr, int* __restrict__ t1tab,
                            int* __restrict__ t2tab) {
  if (threadIdx.x == 0) {
    int o = 0;
    int mtiles[E_];
    for (int e = 0; e < E_; ++e) {
      off[e] = o; o += cnt[e];
      mtiles[e] = (cnt[e] + BM - 1) / BM;
    }
    int n1 = 0;
    for (int e = 0; e < E_; ++e)
      for (int g = 0; g < 4; ++g)
        for (int mt = 0; mt < mtiles[e]; ++mt)
          for (int nl = 0; nl < 4; ++nl)
            t1tab[n1++] = (e << 20) | (mt << 8) | (g * 4 + nl);
    int n2 = 0;
    for (int e = 0; e < E_; ++e)
      for (int sp = 0; sp < 2; ++sp)
        for (int mt = 0; mt < mtiles[e]; ++mt)
          for (int nt = 0; nt < 4; ++nt)
            t2tab[n2++] = (e << 20) | (mt << 8) | (sp << 4) | nt;
    hdr[0] = n1; hdr[1] = n2;
  }
}

// ---------------- grouped per-expert GEMM: 256^2, counted-vmcnt pipeline ------
// Body identical to R4/R6 (best measured). New: 1-D grid over a locality-ordered
// task list with bijective XCD-chunked swizzle (m204): XCD x gets a CONTIGUOUS
// chunk of the task list, so blocks sharing W-panels / A-tiles run on the same
// XCD and hit its L2 instead of re-pulling from LLC (the measured bottleneck).
template <int LAYER, int SPLITK>
__global__ __launch_bounds__(512, 2) void ffn_gemm(
    const unsigned short* __restrict__ xb,
    const unsigned short* __restrict__ hbuf,
    const unsigned short* __restrict__ WT,
    const float* __restrict__ bias,
    const int* __restrict__ cnt, const int* __restrict__ off,
    const int* __restrict__ lists,
    const int* __restrict__ tab, const int* __restrict__ hdr,
    unsigned short* __restrict__ hout,
    float* __restrict__ out)
{
  constexpr int K = (LAYER == 1) ? D_ : H_;
  constexpr int N = (LAYER == 1) ? H_ : D_;
  constexpr int KS = K / SPLITK;
  constexpr int NT = KS / BK;

  const int ntask = hdr[LAYER - 1];
  const int b = blockIdx.x;
  if (b >= ntask) return;
  // bijective XCD-chunk swizzle: consecutive bids round-robin XCDs; give XCD x
  // the contiguous task range starting at x*(q+1) (x<r) / r*(q+1)+(x-r)*q.
  const int q = ntask >> 3, r = ntask & 7;
  const int x = b & 7, ii = b >> 3;
  const int task = (x < r ? x * (q + 1) : r * (q + 1) + (x - r) * q) + ii;

  const int ent = tab[task];
  const int e  = ent >> 20;
  const int m0 = ((ent >> 8) & 0xff) * BM;
  const int sp = (ent >> 4) & 3;
  const int n0 = (ent & 15) * BN;
  const int k0 = sp * KS;
  const int count = cnt[e];
  const int oe = off[e];
  const int* lst = lists + e * T_;

  __shared__ unsigned short sA[2][BM * BK];   // 2 x 32 KB
  __shared__ unsigned short sB[2][BN * BK];   // 2 x 32 KB

  const int tid  = threadIdx.x;
  const int lane = tid & 63;
  const int wv   = tid >> 6;
  const int wm   = (wv >> 2) * 128;
  const int wn   = (wv & 3) * 64;

  // staging: issue i covers rows i*64 + wv*8 + srow
  const int srow   = lane >> 3;
  const int schunk = (lane & 7) * 16;
  const int sgoff  = schunk ^ (srow << 4);

  const char* arow[4];
  const char* brow[4];
#pragma unroll
  for (int i = 0; i < 4; ++i) {
    int rr = i * 64 + wv * 8 + srow;
    int gr = m0 + rr;
    if (LAYER == 1) {
      int tok = (gr < count) ? lst[gr] : lst[m0];
      arow[i] = (const char*)(xb + (size_t)tok * K + k0);
    } else {
      int r2 = (gr < count) ? gr : m0;
      arow[i] = (const char*)(hbuf + (size_t)(oe + r2) * K + k0);
    }
    brow[i] = (const char*)(WT + (size_t)e * N * K + (size_t)(n0 + rr) * K + k0);
  }

  auto stage = [&](int buf, int t) {
    const int kb = t * 128;   // t*BK*2 bytes
#pragma unroll
    for (int i = 0; i < 4; ++i)
      gl16(arow[i] + kb + sgoff, (char*)&sA[buf][0] + (i * 64 + wv * 8) * 128);
#pragma unroll
    for (int i = 0; i < 4; ++i)
      gl16(brow[i] + kb + sgoff, (char*)&sB[buf][0] + (i * 64 + wv * 8) * 128);
  };

  // fragment addressing
  const int lrow = lane & 15;
  const int kg   = lane >> 4;
  const int fswz = (lrow & 7) << 4;

  f32x4 acc[8][4];
#pragma unroll
  for (int i = 0; i < 8; ++i)
#pragma unroll
    for (int j = 0; j < 4; ++j) acc[i][j] = (f32x4){0.f, 0.f, 0.f, 0.f};

  stage(0, 0);
  stage(1, 1);                                      // 16 loads outstanding
  asm volatile("s_waitcnt vmcnt(8)" ::: "memory");  // tile 0 landed
  __builtin_amdgcn_s_barrier();
  MEMFENCE;

  for (int t = 0; t < NT; ++t) {
    const int buf = t & 1;
    // ---- read ALL fragments of tile t into registers ----
    bf16x8 af[8][2], bfm[4][2];
#pragma unroll
    for (int i = 0; i < 8; ++i) {
      const int ra = wm + i * 16 + lrow;
#pragma unroll
      for (int ks = 0; ks < 2; ++ks)
        af[i][ks] = *(const bf16x8*)((const char*)&sA[buf][0] + ra * 128 + ((ks * 64 + kg * 16) ^ fswz));
    }
#pragma unroll
    for (int j = 0; j < 4; ++j) {
      const int rb = wn + j * 16 + lrow;
#pragma unroll
      for (int ks = 0; ks < 2; ++ks)
        bfm[j][ks] = *(const bf16x8*)((const char*)&sB[buf][0] + rb * 128 + ((ks * 64 + kg * 16) ^ fswz));
    }
    MEMFENCE;
    __builtin_amdgcn_s_barrier();   // all waves have queued their reads of buf
    MEMFENCE;
    // ---- stage tile t+2 into the buffer just vacated ----
    if (t + 2 < NT) stage(buf, t + 2);
    // ---- MFMA cluster (compiler inserts lgkmcnt for the reg deps) ----
    __builtin_amdgcn_s_setprio(1);
#pragma unroll
    for (int ks = 0; ks < 2; ++ks)
#pragma unroll
      for (int i = 0; i < 8; ++i)
#pragma unroll
        for (int j = 0; j < 4; ++j)
          acc[i][j] = __builtin_amdgcn_mfma_f32_16x16x32_bf16(af[i][ks], bfm[j][ks], acc[i][j], 0, 0, 0);
    __builtin_amdgcn_s_setprio(0);
    // ---- counted wait: tile t+1 complete, t+2 stays in flight ----
    if (t + 2 < NT) {
      asm volatile("s_waitcnt vmcnt(8)" ::: "memory");
    } else if (t + 1 < NT) {
      asm volatile("s_waitcnt vmcnt(0)" ::: "memory");
    }
    MEMFENCE;
    __builtin_amdgcn_s_barrier();
    MEMFENCE;
  }

  // ---- epilogue ----
  const int rbase = 4 * kg;
#pragma unroll
  for (int i = 0; i < 8; ++i) {
#pragma unroll
    for (int r2 = 0; r2 < 4; ++r2) {
      int row  = wm + i * 16 + rbase + r2;
      int grow = m0 + row;
      if (grow < count) {
#pragma unroll
        for (int j = 0; j < 4; ++j) {
          int col  = wn + j * 16 + lrow;
          int gcol = n0 + col;
          float bv = (SPLITK == 1 || sp == 0) ? bias[(size_t)e * N + gcol] : 0.f;
          float v = acc[i][j][r2] + bv;
          if (LAYER == 1) {
            v = v > 0.f ? v : 0.f;
            hout[(size_t)(oe + grow) * H_ + gcol] = f2bf(v);
          } else {
            int tok = lst[grow];
            atomicAdd(&out[(size_t)tok * D_ + gcol], v);
          }
        }
      }
    }
  }
}

extern "C" void kernel_launch(void* const* d_in, const int* in_sizes, int n_in,
                              void* d_out, int out_size, void* d_ws, size_t ws_size,
                              hipStream_t stream) {
  (void)in_sizes; (void)n_in; (void)out_size; (void)ws_size;
  const float* x  = (const float*)d_in[0];
  const float* W1 = (const float*)d_in[1];
  const float* b1 = (const float*)d_in[2];
  const float* W2 = (const float*)d_in[3];
  const float* b2 = (const float*)d_in[4];
  const float* Wg = (const float*)d_in[5];
  const float* bg = (const float*)d_in[6];

  float* out    = (float*)d_out;               // [T,D]
  float* scores = out + (size_t)T_ * D_;       // [T,E]

  char* ws = (char*)d_ws;
  int* cnt   = (int*)ws;                                   // 32 B
  int* off   = (int*)(ws + 32);                            // 32 B
  int* hdr   = (int*)(ws + 64);                            // 8 B
  int* t1tab = (int*)(ws + 128);                           // 2560 B
  int* t2tab = (int*)(ws + 128 + 4 * MAXT1);               // 1280 B
  int* lists = (int*)(ws + 8192);                          // 128 KB
  unsigned short* xb   = (unsigned short*)(ws + 8192 + 131072);            // 8 MB
  unsigned short* hbuf = (unsigned short*)(ws + 8192 + 131072 + 8388608);  // 64 MB
  unsigned short* WT   = (unsigned short*)(ws + 8192 + 131072 + 8388608 + 67108864); // 64 MB

  hipMemsetAsync(out, 0, (size_t)T_ * D_ * sizeof(float), stream);
  hipMemsetAsync(cnt, 0, 64, stream);

  conv_x_kernel<<<(T_ * D_) / (256 * 8), 256, 0, stream>>>(x, xb);
  gating_kernel<<<T_ / 4, 256, 0, stream>>>(x, Wg, bg, scores, cnt, lists);
  scan_kernel<<<1, 64, 0, stream>>>(cnt, off, hdr, t1tab, t2tab);

  // W1 [E,1024,4096] -> W1T [E,4096,1024]
  transpose_conv<<<dim3(H_ / 64, D_ / 64, E_), 256, 0, stream>>>(W1, WT, D_, H_);
  ffn_gemm<1, 1><<<MAXT1, 512, 0, stream>>>(
      xb, hbuf, WT, b1, cnt, off, lists, t1tab, hdr, hbuf, nullptr);

  // W2 [E,4096,1024] -> W2T [E,1024,4096]  (reuses WT after gemm1)
  transpose_conv<<<dim3(D_ / 64, H_ / 64, E_), 256, 0, stream>>>(W2, WT, H_, D_);
  ffn_gemm<2, 2><<<MAXT2, 512, 0, stream>>>(
      xb, hbuf, WT, b2, cnt, off, lists, t2tab, hdr, nullptr, out);
}

// Round 9
// 496.937 us; speedup vs baseline: 1.0762x; 1.0317x over previous
//
#include <hip/hip_runtime.h>
#include <hip/hip_bf16.h>
#include <stdint.h>

#define B_ 4
#define S_ 1024
#define D_ 1024
#define H_ 4096
#define E_ 8
#define T_ (B_*S_)   // 4096 tokens

#define GBM 128      // GEMM tile
#define BK 64        // 128 bytes bf16 per row per K-tile
#define MAXT1 2432
#define MAXT2 1280

typedef __bf16 bf16x8 __attribute__((ext_vector_type(8)));
typedef float f32x4 __attribute__((ext_vector_type(4)));
typedef unsigned short ushort8 __attribute__((ext_vector_type(8)));

__device__ __forceinline__ unsigned short f2bf(float f) {
  union { float f; uint32_t u; } v; v.f = f;
  uint32_t u = v.u;
  u += 0x7fff + ((u >> 16) & 1);   // round-to-nearest-even
  return (unsigned short)(u >> 16);
}

// async global->LDS, 16B per lane; LDS dest is WAVE-UNIFORM base, HW scatters lane*16
__device__ __forceinline__ void gl16(const void* g, void* l) {
  __builtin_amdgcn_global_load_lds(
      (const __attribute__((address_space(1))) void*)g,
      (__attribute__((address_space(3))) void*)l,
      16, 0, 0);
}

// ---------------- x fp32 -> bf16 ----------------
__global__ __launch_bounds__(256) void conv_x_kernel(
    const float* __restrict__ x, unsigned short* __restrict__ xb) {
  size_t i = ((size_t)blockIdx.x * 256 + threadIdx.x) * 8;
  const float4* s = (const float4*)(x + i);
  float4 v0 = s[0], v1 = s[1];
  ushort8 w;
  w[0]=f2bf(v0.x); w[1]=f2bf(v0.y); w[2]=f2bf(v0.z); w[3]=f2bf(v0.w);
  w[4]=f2bf(v1.x); w[5]=f2bf(v1.y); w[6]=f2bf(v1.z); w[7]=f2bf(v1.w);
  *(ushort8*)(xb + i) = w;
}

// ---------------- W fp32 [E][R][C] -> bf16 [E][C][R] ----------------
__global__ __launch_bounds__(256) void transpose_conv(
    const float* __restrict__ in, unsigned short* __restrict__ outp,
    int R, int C) {
  __shared__ float tile[64][68];
  const int e = blockIdx.z;
  const size_t eoff = (size_t)e * R * C;
  const int r0 = blockIdx.y * 64, c0 = blockIdx.x * 64;
  const int t = threadIdx.x;
  {
    const int r = t >> 2, cq = (t & 3) * 16;
    const float4* s4 = (const float4*)(in + eoff + (size_t)(r0 + r) * C + (c0 + cq));
#pragma unroll
    for (int i = 0; i < 4; ++i)
      *(float4*)&tile[r][cq + i * 4] = s4[i];
  }
  __syncthreads();
  {
    const int c = t >> 2, r8 = (t & 3) * 16;
    unsigned short* dst = outp + eoff + (size_t)(c0 + c) * R + (r0 + r8);
    ushort8 w0, w1;
#pragma unroll
    for (int j = 0; j < 8; ++j) {
      w0[j] = f2bf(tile[r8 + j][c]);
      w1[j] = f2bf(tile[r8 + 8 + j][c]);
    }
    *(ushort8*)dst = w0;
    *(ushort8*)(dst + 8) = w1;
  }
}

// ---------------- gating: scores + top-2 routing ----------------
__global__ __launch_bounds__(256) void gating_kernel(
    const float* __restrict__ x, const float* __restrict__ Wg,
    const float* __restrict__ bg, float* __restrict__ scores,
    int* __restrict__ cnt, int* __restrict__ lists) {
  int t = blockIdx.x * 4 + (threadIdx.x >> 6);
  int l = threadIdx.x & 63;
  float acc[E_];
#pragma unroll
  for (int e = 0; e < E_; ++e) acc[e] = 0.f;
  const float* xr = x + (size_t)t * D_;
  for (int k = l; k < D_; k += 64) {
    float xv = xr[k];
    const float4* w = (const float4*)(Wg + (size_t)k * E_);
    float4 w0 = w[0], w1 = w[1];
    acc[0] += xv * w0.x; acc[1] += xv * w0.y; acc[2] += xv * w0.z; acc[3] += xv * w0.w;
    acc[4] += xv * w1.x; acc[5] += xv * w1.y; acc[6] += xv * w1.z; acc[7] += xv * w1.w;
  }
#pragma unroll
  for (int off = 32; off > 0; off >>= 1)
#pragma unroll
    for (int e = 0; e < E_; ++e) acc[e] += __shfl_xor(acc[e], off, 64);
  if (l == 0) {
    float s[E_];
#pragma unroll
    for (int e = 0; e < E_; ++e) {
      s[e] = acc[e] + bg[e];
      scores[(size_t)t * E_ + e] = s[e];
    }
    int i1 = 0; float m1 = -1e30f;
#pragma unroll
    for (int e = 0; e < E_; ++e) if (s[e] > m1) { m1 = s[e]; i1 = e; }
    int i2 = -1; float m2 = -1e30f;
#pragma unroll
    for (int e = 0; e < E_; ++e) if (e != i1 && s[e] > m2) { m2 = s[e]; i2 = e; }
    int p1 = atomicAdd(&cnt[i1], 1); lists[i1 * T_ + p1] = t;
    int p2 = atomicAdd(&cnt[i2], 1); lists[i2 * T_ + p2] = t;
  }
}

// scan + locality-ordered task tables (128-row m-tiles).
// word: e<<16 | mt<<8 | sp<<6 | nt
// GEMM1 order (e, nt, mt): one expert's window per XCD chunk; B-panel (256KB)
// L2-resident across mt, expert's A (~2MB) L2-resident across nt.
// GEMM2 order (e, sp, nt, mt): B-panel resident across mt, A-split across nt.
__global__ void scan_kernel(const int* __restrict__ cnt, int* __restrict__ off,
                            int* __restrict__ hdr, int* __restrict__ t1tab,
                            int* __restrict__ t2tab) {
  if (threadIdx.x == 0) {
    int o = 0;
    int mtiles[E_];
    for (int e = 0; e < E_; ++e) {
      off[e] = o; o += cnt[e];
      mtiles[e] = (cnt[e] + GBM - 1) / GBM;
    }
    int n1 = 0;
    for (int e = 0; e < E_; ++e)
      for (int nt = 0; nt < H_ / GBM; ++nt)
        for (int mt = 0; mt < mtiles[e]; ++mt)
          t1tab[n1++] = (e << 16) | (mt << 8) | nt;
    int n2 = 0;
    for (int e = 0; e < E_; ++e)
      for (int sp = 0; sp < 2; ++sp)
        for (int nt = 0; nt < D_ / GBM; ++nt)
          for (int mt = 0; mt < mtiles[e]; ++mt)
            t2tab[n2++] = (e << 16) | (mt << 8) | (sp << 6) | nt;
    hdr[0] = n1; hdr[1] = n2;
  }
}

// ---------------- grouped per-expert GEMM: 128^2 m97-structure ---------------
// 256 thr = 4 waves (2x2), per-wave 64x64 output (4x4 frags of 16x16).
// LDS: single buffer A 16KB + B 16KB = 32KB -> 3 blocks/CU (launch_bounds 256,3)
// -> cross-block TLP hides the barrier vmcnt drain (m97/m114 mechanism).
// Rows 128B; swizzle byte^=((row&7)<<4) baked into per-lane GLOBAL source
// (gload_lds writes linearly); same XOR on ds_read. Verified conflict-free.
template <int LAYER, int SPLITK>
__global__ __launch_bounds__(256, 3) void ffn_gemm(
    const unsigned short* __restrict__ xb,
    const unsigned short* __restrict__ hbuf,
    const unsigned short* __restrict__ WT,
    const float* __restrict__ bias,
    const int* __restrict__ cnt, const int* __restrict__ off,
    const int* __restrict__ lists,
    const int* __restrict__ tab, const int* __restrict__ hdr,
    unsigned short* __restrict__ hout,
    float* __restrict__ out)
{
  constexpr int K = (LAYER == 1) ? D_ : H_;
  constexpr int N = (LAYER == 1) ? H_ : D_;
  constexpr int KS = K / SPLITK;
  constexpr int NT = KS / BK;

  const int ntask = hdr[LAYER - 1];
  const int b = blockIdx.x;
  if (b >= ntask) return;
  // bijective XCD-chunk swizzle (m204): XCD x owns a contiguous task range.
  const int q = ntask >> 3, r = ntask & 7;
  const int x = b & 7, ii = b >> 3;
  const int task = (x < r ? x * (q + 1) : r * (q + 1) + (x - r) * q) + ii;

  const int ent = tab[task];
  const int e  = ent >> 16;
  const int m0 = ((ent >> 8) & 0xff) * GBM;
  const int sp = (ent >> 6) & 3;
  const int n0 = (ent & 63) * GBM;
  const int k0 = sp * KS;
  const int count = cnt[e];
  const int oe = off[e];
  const int* lst = lists + e * T_;

  __shared__ unsigned short sA[GBM * BK];   // 16 KB
  __shared__ unsigned short sB[GBM * BK];   // 16 KB

  const int tid  = threadIdx.x;
  const int lane = tid & 63;
  const int wv   = tid >> 6;
  const int wm   = (wv >> 1) * 64;
  const int wn   = (wv & 1) * 64;

  // staging: issue i covers rows i*32 + wv*8 + srow (i=0..3 -> 128 rows)
  const int srow   = lane >> 3;
  const int schunk = (lane & 7) * 16;
  const int sgoff  = schunk ^ (srow << 4);

  const char* arow[4];
  const char* brow[4];
#pragma unroll
  for (int i = 0; i < 4; ++i) {
    int rr = i * 32 + wv * 8 + srow;
    int gr = m0 + rr;
    if (LAYER == 1) {
      int tok = (gr < count) ? lst[gr] : lst[m0];
      arow[i] = (const char*)(xb + (size_t)tok * K + k0);
    } else {
      int r2 = (gr < count) ? gr : m0;
      arow[i] = (const char*)(hbuf + (size_t)(oe + r2) * K + k0);
    }
    brow[i] = (const char*)(WT + (size_t)e * N * K + (size_t)(n0 + rr) * K + k0);
  }

  // fragment addressing
  const int lrow = lane & 15;
  const int kg   = lane >> 4;
  const int fswz = (lrow & 7) << 4;

  f32x4 acc[4][4];
#pragma unroll
  for (int i = 0; i < 4; ++i)
#pragma unroll
    for (int j = 0; j < 4; ++j) acc[i][j] = (f32x4){0.f, 0.f, 0.f, 0.f};

#pragma unroll 1
  for (int t = 0; t < NT; ++t) {
    const int kb = t * 128;   // bytes along K
#pragma unroll
    for (int i = 0; i < 4; ++i)
      gl16(arow[i] + kb + sgoff, (char*)sA + (i * 32 + wv * 8) * 128);
#pragma unroll
    for (int i = 0; i < 4; ++i)
      gl16(brow[i] + kb + sgoff, (char*)sB + (i * 32 + wv * 8) * 128);
    __syncthreads();   // drains vmcnt -> tile ready; TLP from 3 blocks/CU hides it
#pragma unroll
    for (int ks = 0; ks < 2; ++ks) {
      bf16x8 af[4], bfm[4];
      const int kbyte = ks * 64 + kg * 16;
#pragma unroll
      for (int i = 0; i < 4; ++i) {
        af[i]  = *(const bf16x8*)((const char*)sA + (wm + i * 16 + lrow) * 128 + (kbyte ^ fswz));
        bfm[i] = *(const bf16x8*)((const char*)sB + (wn + i * 16 + lrow) * 128 + (kbyte ^ fswz));
      }
#pragma unroll
      for (int i = 0; i < 4; ++i)
#pragma unroll
        for (int j = 0; j < 4; ++j)
          acc[i][j] = __builtin_amdgcn_mfma_f32_16x16x32_bf16(af[i], bfm[j], acc[i][j], 0, 0, 0);
    }
    __syncthreads();   // all reads done before next stage overwrites
  }

  // ---- epilogue ----
  const int rbase = 4 * kg;
#pragma unroll
  for (int i = 0; i < 4; ++i) {
#pragma unroll
    for (int r2 = 0; r2 < 4; ++r2) {
      int row  = wm + i * 16 + rbase + r2;
      int grow = m0 + row;
      if (grow < count) {
#pragma unroll
        for (int j = 0; j < 4; ++j) {
          int col  = wn + j * 16 + lrow;
          int gcol = n0 + col;
          float bv = (SPLITK == 1 || sp == 0) ? bias[(size_t)e * N + gcol] : 0.f;
          float v = acc[i][j][r2] + bv;
          if (LAYER == 1) {
            v = v > 0.f ? v : 0.f;
            hout[(size_t)(oe + grow) * H_ + gcol] = f2bf(v);
          } else {
            int tok = lst[grow];
            atomicAdd(&out[(size_t)tok * D_ + gcol], v);
          }
        }
      }
    }
  }
}

extern "C" void kernel_launch(void* const* d_in, const int* in_sizes, int n_in,
                              void* d_out, int out_size, void* d_ws, size_t ws_size,
                              hipStream_t stream) {
  (void)in_sizes; (void)n_in; (void)out_size; (void)ws_size;
  const float* x  = (const float*)d_in[0];
  const float* W1 = (const float*)d_in[1];
  const float* b1 = (const float*)d_in[2];
  const float* W2 = (const float*)d_in[3];
  const float* b2 = (const float*)d_in[4];
  const float* Wg = (const float*)d_in[5];
  const float* bg = (const float*)d_in[6];

  float* out    = (float*)d_out;               // [T,D]
  float* scores = out + (size_t)T_ * D_;       // [T,E]

  char* ws = (char*)d_ws;
  int* cnt   = (int*)ws;                                   // 32 B
  int* off   = (int*)(ws + 32);                            // 32 B
  int* hdr   = (int*)(ws + 64);                            // 8 B
  int* t1tab = (int*)(ws + 128);                           // 9728 B
  int* t2tab = (int*)(ws + 10240);                         // 5120 B
  int* lists = (int*)(ws + 16384);                         // 128 KB
  unsigned short* xb   = (unsigned short*)(ws + 16384 + 131072);            // 8 MB
  unsigned short* hbuf = (unsigned short*)(ws + 16384 + 131072 + 8388608);  // 64 MB
  unsigned short* WT   = (unsigned short*)(ws + 16384 + 131072 + 8388608 + 67108864); // 64 MB

  hipMemsetAsync(out, 0, (size_t)T_ * D_ * sizeof(float), stream);
  hipMemsetAsync(cnt, 0, 64, stream);

  conv_x_kernel<<<(T_ * D_) / (256 * 8), 256, 0, stream>>>(x, xb);
  gating_kernel<<<T_ / 4, 256, 0, stream>>>(x, Wg, bg, scores, cnt, lists);
  scan_kernel<<<1, 64, 0, stream>>>(cnt, off, hdr, t1tab, t2tab);

  // W1 [E,1024,4096] -> W1T [E,4096,1024]
  transpose_conv<<<dim3(H_ / 64, D_ / 64, E_), 256, 0, stream>>>(W1, WT, D_, H_);
  ffn_gemm<1, 1><<<MAXT1, 256, 0, stream>>>(
      xb, hbuf, WT, b1, cnt, off, lists, t1tab, hdr, hbuf, nullptr);

  // W2 [E,4096,1024] -> W2T [E,1024,4096]  (reuses WT after gemm1)
  transpose_conv<<<dim3(D_ / 64, H_ / 64, E_), 256, 0, stream>>>(W2, WT, H_, D_);
  ffn_gemm<2, 2><<<MAXT2, 256, 0, stream>>>(
      xb, hbuf, WT, b2, cnt, off, lists, t2tab, hdr, nullptr, out);
}

// Round 10
// 492.827 us; speedup vs baseline: 1.0851x; 1.0083x over previous
//
#include <hip/hip_runtime.h>
#include <hip/hip_bf16.h>
#include <stdint.h>

#define B_ 4
#define S_ 1024
#define D_ 1024
#define H_ 4096
#define E_ 8
#define T_ (B_*S_)   // 4096 tokens

#define GBM 128      // GEMM tile
#define BK 64        // 128 bytes bf16 per row per K-tile
#define MAXT1 2432
#define MAXT2 1280

typedef __bf16 bf16x8 __attribute__((ext_vector_type(8)));
typedef float f32x4 __attribute__((ext_vector_type(4)));
typedef unsigned short ushort8 __attribute__((ext_vector_type(8)));
typedef unsigned short ushort4v __attribute__((ext_vector_type(4)));

__device__ __forceinline__ unsigned short f2bf(float f) {
  union { float f; uint32_t u; } v; v.f = f;
  uint32_t u = v.u;
  u += 0x7fff + ((u >> 16) & 1);   // round-to-nearest-even
  return (unsigned short)(u >> 16);
}

// async global->LDS, 16B per lane; LDS dest is WAVE-UNIFORM base, HW scatters lane*16
__device__ __forceinline__ void gl16(const void* g, void* l) {
  __builtin_amdgcn_global_load_lds(
      (const __attribute__((address_space(1))) void*)g,
      (__attribute__((address_space(3))) void*)l,
      16, 0, 0);
}

// ---------------- W fp32 [E][R][C] -> bf16 [E][C][R], bf16 LDS tile ----------
// Phase1: thread t reads 16 floats of row r=t>>2 (cols (t&3)*16..+15), converts,
// writes 2x ushort8 to tile[r][cseg] (stride 66 shorts = 33 banks: <=2-way).
// Phase2: thread t reads column c=t>>2, rows (t&3)*16..+15 (scalar u16, ~4-way),
// stores 32B contiguous to out row c -> fully coalesced 128B per 4 lanes.
__global__ __launch_bounds__(256) void transpose_conv(
    const float* __restrict__ in, unsigned short* __restrict__ outp,
    int R, int C) {
  __shared__ unsigned short tile[64][66];
  const int e = blockIdx.z;
  const size_t eoff = (size_t)e * R * C;
  const int r0 = blockIdx.y * 64, c0 = blockIdx.x * 64;
  const int t = threadIdx.x;
  {
    const int r = t >> 2, cseg = (t & 3) * 16;
    const float4* s4 = (const float4*)(in + eoff + (size_t)(r0 + r) * C + (c0 + cseg));
    float4 v0 = s4[0], v1 = s4[1], v2 = s4[2], v3 = s4[3];
    ushort8 w0, w1;
    w0[0]=f2bf(v0.x); w0[1]=f2bf(v0.y); w0[2]=f2bf(v0.z); w0[3]=f2bf(v0.w);
    w0[4]=f2bf(v1.x); w0[5]=f2bf(v1.y); w0[6]=f2bf(v1.z); w0[7]=f2bf(v1.w);
    w1[0]=f2bf(v2.x); w1[1]=f2bf(v2.y); w1[2]=f2bf(v2.z); w1[3]=f2bf(v2.w);
    w1[4]=f2bf(v3.x); w1[5]=f2bf(v3.y); w1[6]=f2bf(v3.z); w1[7]=f2bf(v3.w);
    *(ushort8*)&tile[r][cseg]     = w0;
    *(ushort8*)&tile[r][cseg + 8] = w1;
  }
  __syncthreads();
  {
    const int c = t >> 2, rseg = (t & 3) * 16;
    ushort8 w0, w1;
#pragma unroll
    for (int j = 0; j < 8; ++j) {
      w0[j] = tile[rseg + j][c];
      w1[j] = tile[rseg + 8 + j][c];
    }
    unsigned short* dst = outp + eoff + (size_t)(c0 + c) * R + (r0 + rseg);
    *(ushort8*)dst       = w0;
    *(ushort8*)(dst + 8) = w1;
  }
}

// ---------------- gating + x->bf16 fused ----------------
__global__ __launch_bounds__(256) void gating_kernel(
    const float* __restrict__ x, const float* __restrict__ Wg,
    const float* __restrict__ bg, float* __restrict__ scores,
    unsigned short* __restrict__ xb,
    int* __restrict__ cnt, int* __restrict__ lists) {
  int t = blockIdx.x * 4 + (threadIdx.x >> 6);
  int l = threadIdx.x & 63;
  float acc[E_];
#pragma unroll
  for (int e = 0; e < E_; ++e) acc[e] = 0.f;
  const float* xr = x + (size_t)t * D_;
  unsigned short* xbr = xb + (size_t)t * D_;
  for (int k4 = l * 4; k4 < D_; k4 += 256) {
    float4 xv = *(const float4*)(xr + k4);
    ushort4v wq;
    wq[0] = f2bf(xv.x); wq[1] = f2bf(xv.y); wq[2] = f2bf(xv.z); wq[3] = f2bf(xv.w);
    *(ushort4v*)(xbr + k4) = wq;
#pragma unroll
    for (int q = 0; q < 4; ++q) {
      float xs = (q == 0) ? xv.x : (q == 1) ? xv.y : (q == 2) ? xv.z : xv.w;
      const float4* w = (const float4*)(Wg + (size_t)(k4 + q) * E_);
      float4 w0 = w[0], w1 = w[1];
      acc[0] += xs * w0.x; acc[1] += xs * w0.y; acc[2] += xs * w0.z; acc[3] += xs * w0.w;
      acc[4] += xs * w1.x; acc[5] += xs * w1.y; acc[6] += xs * w1.z; acc[7] += xs * w1.w;
    }
  }
#pragma unroll
  for (int off = 32; off > 0; off >>= 1)
#pragma unroll
    for (int e = 0; e < E_; ++e) acc[e] += __shfl_xor(acc[e], off, 64);
  if (l == 0) {
    float s[E_];
#pragma unroll
    for (int e = 0; e < E_; ++e) {
      s[e] = acc[e] + bg[e];
      scores[(size_t)t * E_ + e] = s[e];
    }
    int i1 = 0; float m1 = -1e30f;
#pragma unroll
    for (int e = 0; e < E_; ++e) if (s[e] > m1) { m1 = s[e]; i1 = e; }
    int i2 = -1; float m2 = -1e30f;
#pragma unroll
    for (int e = 0; e < E_; ++e) if (e != i1 && s[e] > m2) { m2 = s[e]; i2 = e; }
    int p1 = atomicAdd(&cnt[i1], 1); lists[i1 * T_ + p1] = t;
    int p2 = atomicAdd(&cnt[i2], 1); lists[i2 * T_ + p2] = t;
  }
}

// scan + locality-ordered task tables (128-row m-tiles).
// word: e<<16 | mt<<8 | sp<<6 | nt
__global__ void scan_kernel(const int* __restrict__ cnt, int* __restrict__ off,
                            int* __restrict__ hdr, int* __restrict__ t1tab,
                            int* __restrict__ t2tab) {
  if (threadIdx.x == 0) {
    int o = 0;
    int mtiles[E_];
    for (int e = 0; e < E_; ++e) {
      off[e] = o; o += cnt[e];
      mtiles[e] = (cnt[e] + GBM - 1) / GBM;
    }
    int n1 = 0;
    for (int e = 0; e < E_; ++e)
      for (int nt = 0; nt < H_ / GBM; ++nt)
        for (int mt = 0; mt < mtiles[e]; ++mt)
          t1tab[n1++] = (e << 16) | (mt << 8) | nt;
    int n2 = 0;
    for (int e = 0; e < E_; ++e)
      for (int sp = 0; sp < 2; ++sp)
        for (int nt = 0; nt < D_ / GBM; ++nt)
          for (int mt = 0; mt < mtiles[e]; ++mt)
            t2tab[n2++] = (e << 16) | (mt << 8) | (sp << 6) | nt;
    hdr[0] = n1; hdr[1] = n2;
  }
}

// ---------------- grouped per-expert GEMM: 128^2 m97-structure ---------------
// (body unchanged from R9 — best measured: 157us/GEMM, 437 TF grouped)
template <int LAYER, int SPLITK>
__global__ __launch_bounds__(256, 4) void ffn_gemm(
    const unsigned short* __restrict__ xb,
    const unsigned short* __restrict__ hbuf,
    const unsigned short* __restrict__ WT,
    const float* __restrict__ bias,
    const int* __restrict__ cnt, const int* __restrict__ off,
    const int* __restrict__ lists,
    const int* __restrict__ tab, const int* __restrict__ hdr,
    unsigned short* __restrict__ hout,
    float* __restrict__ out)
{
  constexpr int K = (LAYER == 1) ? D_ : H_;
  constexpr int N = (LAYER == 1) ? H_ : D_;
  constexpr int KS = K / SPLITK;
  constexpr int NT = KS / BK;

  const int ntask = hdr[LAYER - 1];
  const int b = blockIdx.x;
  if (b >= ntask) return;
  // bijective XCD-chunk swizzle (m204): XCD x owns a contiguous task range.
  const int q = ntask >> 3, r = ntask & 7;
  const int x = b & 7, ii = b >> 3;
  const int task = (x < r ? x * (q + 1) : r * (q + 1) + (x - r) * q) + ii;

  const int ent = tab[task];
  const int e  = ent >> 16;
  const int m0 = ((ent >> 8) & 0xff) * GBM;
  const int sp = (ent >> 6) & 3;
  const int n0 = (ent & 63) * GBM;
  const int k0 = sp * KS;
  const int count = cnt[e];
  const int oe = off[e];
  const int* lst = lists + e * T_;

  __shared__ unsigned short sA[GBM * BK];   // 16 KB
  __shared__ unsigned short sB[GBM * BK];   // 16 KB

  const int tid  = threadIdx.x;
  const int lane = tid & 63;
  const int wv   = tid >> 6;
  const int wm   = (wv >> 1) * 64;
  const int wn   = (wv & 1) * 64;

  const int srow   = lane >> 3;
  const int schunk = (lane & 7) * 16;
  const int sgoff  = schunk ^ (srow << 4);

  const char* arow[4];
  const char* brow[4];
#pragma unroll
  for (int i = 0; i < 4; ++i) {
    int rr = i * 32 + wv * 8 + srow;
    int gr = m0 + rr;
    if (LAYER == 1) {
      int tok = (gr < count) ? lst[gr] : lst[m0];
      arow[i] = (const char*)(xb + (size_t)tok * K + k0);
    } else {
      int r2 = (gr < count) ? gr : m0;
      arow[i] = (const char*)(hbuf + (size_t)(oe + r2) * K + k0);
    }
    brow[i] = (const char*)(WT + (size_t)e * N * K + (size_t)(n0 + rr) * K + k0);
  }

  const int lrow = lane & 15;
  const int kg   = lane >> 4;
  const int fswz = (lrow & 7) << 4;

  f32x4 acc[4][4];
#pragma unroll
  for (int i = 0; i < 4; ++i)
#pragma unroll
    for (int j = 0; j < 4; ++j) acc[i][j] = (f32x4){0.f, 0.f, 0.f, 0.f};

#pragma unroll 1
  for (int t = 0; t < NT; ++t) {
    const int kb = t * 128;   // bytes along K
#pragma unroll
    for (int i = 0; i < 4; ++i)
      gl16(arow[i] + kb + sgoff, (char*)sA + (i * 32 + wv * 8) * 128);
#pragma unroll
    for (int i = 0; i < 4; ++i)
      gl16(brow[i] + kb + sgoff, (char*)sB + (i * 32 + wv * 8) * 128);
    __syncthreads();   // drains vmcnt -> tile ready; cross-block TLP hides it
#pragma unroll
    for (int ks = 0; ks < 2; ++ks) {
      bf16x8 af[4], bfm[4];
      const int kbyte = ks * 64 + kg * 16;
#pragma unroll
      for (int i = 0; i < 4; ++i) {
        af[i]  = *(const bf16x8*)((const char*)sA + (wm + i * 16 + lrow) * 128 + (kbyte ^ fswz));
        bfm[i] = *(const bf16x8*)((const char*)sB + (wn + i * 16 + lrow) * 128 + (kbyte ^ fswz));
      }
#pragma unroll
      for (int i = 0; i < 4; ++i)
#pragma unroll
        for (int j = 0; j < 4; ++j)
          acc[i][j] = __builtin_amdgcn_mfma_f32_16x16x32_bf16(af[i], bfm[j], acc[i][j], 0, 0, 0);
    }
    __syncthreads();   // all reads done before next stage overwrites
  }

  // ---- epilogue ----
  const int rbase = 4 * kg;
#pragma unroll
  for (int i = 0; i < 4; ++i) {
#pragma unroll
    for (int r2 = 0; r2 < 4; ++r2) {
      int row  = wm + i * 16 + rbase + r2;
      int grow = m0 + row;
      if (grow < count) {
#pragma unroll
        for (int j = 0; j < 4; ++j) {
          int col  = wn + j * 16 + lrow;
          int gcol = n0 + col;
          float bv = (SPLITK == 1 || sp == 0) ? bias[(size_t)e * N + gcol] : 0.f;
          float v = acc[i][j][r2] + bv;
          if (LAYER == 1) {
            v = v > 0.f ? v : 0.f;
            hout[(size_t)(oe + grow) * H_ + gcol] = f2bf(v);
          } else {
            int tok = lst[grow];
            atomicAdd(&out[(size_t)tok * D_ + gcol], v);
          }
        }
      }
    }
  }
}

extern "C" void kernel_launch(void* const* d_in, const int* in_sizes, int n_in,
                              void* d_out, int out_size, void* d_ws, size_t ws_size,
                              hipStream_t stream) {
  (void)in_sizes; (void)n_in; (void)out_size; (void)ws_size;
  const float* x  = (const float*)d_in[0];
  const float* W1 = (const float*)d_in[1];
  const float* b1 = (const float*)d_in[2];
  const float* W2 = (const float*)d_in[3];
  const float* b2 = (const float*)d_in[4];
  const float* Wg = (const float*)d_in[5];
  const float* bg = (const float*)d_in[6];

  float* out    = (float*)d_out;               // [T,D]
  float* scores = out + (size_t)T_ * D_;       // [T,E]

  char* ws = (char*)d_ws;
  int* cnt   = (int*)ws;                                   // 32 B
  int* off   = (int*)(ws + 32);                            // 32 B
  int* hdr   = (int*)(ws + 64);                            // 8 B
  int* t1tab = (int*)(ws + 128);                           // 9728 B
  int* t2tab = (int*)(ws + 10240);                         // 5120 B
  int* lists = (int*)(ws + 16384);                         // 128 KB
  unsigned short* xb   = (unsigned short*)(ws + 16384 + 131072);            // 8 MB
  unsigned short* hbuf = (unsigned short*)(ws + 16384 + 131072 + 8388608);  // 64 MB
  unsigned short* WT   = (unsigned short*)(ws + 16384 + 131072 + 8388608 + 67108864); // 64 MB

  hipMemsetAsync(out, 0, (size_t)T_ * D_ * sizeof(float), stream);
  hipMemsetAsync(cnt, 0, 64, stream);

  gating_kernel<<<T_ / 4, 256, 0, stream>>>(x, Wg, bg, scores, xb, cnt, lists);
  scan_kernel<<<1, 64, 0, stream>>>(cnt, off, hdr, t1tab, t2tab);

  // W1 [E,1024,4096] -> W1T [E,4096,1024]
  transpose_conv<<<dim3(H_ / 64, D_ / 64, E_), 256, 0, stream>>>(W1, WT, D_, H_);
  ffn_gemm<1, 1><<<MAXT1, 256, 0, stream>>>(
      xb, hbuf, WT, b1, cnt, off, lists, t1tab, hdr, hbuf, nullptr);

  // W2 [E,4096,1024] -> W2T [E,1024,4096]  (reuses WT after gemm1)
  transpose_conv<<<dim3(D_ / 64, H_ / 64, E_), 256, 0, stream>>>(W2, WT, H_, D_);
  ffn_gemm<2, 2><<<MAXT2, 256, 0, stream>>>(
      xb, hbuf, WT, b2, cnt, off, lists, t2tab, hdr, nullptr, out);
}